// Round 9
// baseline (391.752 us; speedup 1.0000x reference)
//
#include <hip/hip_runtime.h>
#include <cstdint>

#define VOCAB_N 50000
#define EMB_N   16
#define HID_N   32
#define B_N     4096
#define T_N     500
#define LOG2E     1.4426950408889634f
#define TWOLOG2E  2.8853900817779268f

typedef __attribute__((ext_vector_type(2))) float f32x2;

__device__ __forceinline__ float frcp(float x) { return __builtin_amdgcn_rcpf(x); }
#define FMA2(A, B, C) __builtin_elementwise_fma((A), (B), (C))

// ---------------------------------------------------------------------------
// proj2[v][l] = { -log2e * z_pre[l],  sBl * z_pre[64+l] },
//   z_pre = bias + emb[v] . W,  sBl = (l<32 ? +2*log2e : -log2e)
// (pre-scaled so the scan's exp2 consumes z directly)
// ---------------------------------------------------------------------------
__global__ void build_proj2s_kernel(const float* __restrict__ emb,
                                    const float* __restrict__ W,
                                    const float* __restrict__ bias,
                                    float2* __restrict__ proj2) {
  __shared__ float Wl[EMB_N * 128];
  __shared__ float bl[128];
  const int tid = threadIdx.x;
  for (int i = tid; i < EMB_N * 128 / 4; i += 256)
    reinterpret_cast<float4*>(Wl)[i] = reinterpret_cast<const float4*>(W)[i];
  if (tid < 32)
    reinterpret_cast<float4*>(bl)[tid] = reinterpret_cast<const float4*>(bias)[tid];
  __syncthreads();

  const int gid = blockIdx.x * 256 + tid;
  const int v = gid >> 6;
  const int l = gid & 63;
  if (v >= VOCAB_N) return;

  const float4* ev = reinterpret_cast<const float4*>(emb + (size_t)v * EMB_N);
  float4 e0 = ev[0], e1 = ev[1], e2 = ev[2], e3 = ev[3];
  const float em[16] = {e0.x,e0.y,e0.z,e0.w, e1.x,e1.y,e1.z,e1.w,
                        e2.x,e2.y,e2.z,e2.w, e3.x,e3.y,e3.z,e3.w};
  float a0 = bl[l], a1 = bl[64 + l];
#pragma unroll
  for (int e = 0; e < EMB_N; ++e) {
    a0 = fmaf(em[e], Wl[e * 128 + l],      a0);
    a1 = fmaf(em[e], Wl[e * 128 + 64 + l], a1);
  }
  const float sBl = (l < 32) ? TWOLOG2E : -LOG2E;
  proj2[(size_t)v * 64 + l] = make_float2(a0 * -LOG2E, a1 * sBl);
}

// ---------------------------------------------------------------------------
// Scan: 1 wave per batch row (block = 64 thr, grid = 4096). Lane l owns
// z-cols {l, 64+l}. Matvec: 32 v_pk_fma_f32 over k-pairs; weights pre-scaled
// so exp2 takes z directly. launch_bounds(64,3): 170-reg cap so the 64
// weight VGPRs stay in the arch file (no AGPR shadow reads).
// ---------------------------------------------------------------------------
#define KP(HX, HY, K2, AA, BB)                                                \
    (AA) = FMA2(((f32x2){(HX), (HY)}), wA[K2], (AA));                         \
    (BB) = FMA2(((f32x2){(HX), (HY)}), wB[K2], (BB));

#define STEP(STOK, PTOK, PC)                                                  \
  {                                                                           \
    float4 hq0 = *reinterpret_cast<const float4*>(hbuf + 0);                  \
    float4 hq1 = *reinterpret_cast<const float4*>(hbuf + 4);                  \
    float4 hq2 = *reinterpret_cast<const float4*>(hbuf + 8);                  \
    float4 hq3 = *reinterpret_cast<const float4*>(hbuf + 12);                 \
    float4 hq4 = *reinterpret_cast<const float4*>(hbuf + 16);                 \
    float4 hq5 = *reinterpret_cast<const float4*>(hbuf + 20);                 \
    float4 hq6 = *reinterpret_cast<const float4*>(hbuf + 24);                 \
    float4 hq7 = *reinterpret_cast<const float4*>(hbuf + 28);                 \
    const float xA = (PC).x, xB = (PC).y;                                     \
    (PC) = proj2[(size_t)(PTOK) * 64 + l];   /* prefetch t+2 */               \
    f32x2 a0 = {xA, 0.f}, a1 = {0.f, 0.f};                                    \
    f32x2 b0 = {xB, 0.f}, b1 = {0.f, 0.f};                                    \
    KP(hq0.x, hq0.y,  0, a0, b0)  KP(hq0.z, hq0.w,  1, a0, b0)                \
    KP(hq1.x, hq1.y,  2, a0, b0)  KP(hq1.z, hq1.w,  3, a0, b0)                \
    KP(hq2.x, hq2.y,  4, a0, b0)  KP(hq2.z, hq2.w,  5, a0, b0)                \
    KP(hq3.x, hq3.y,  6, a0, b0)  KP(hq3.z, hq3.w,  7, a0, b0)                \
    KP(hq4.x, hq4.y,  8, a1, b1)  KP(hq4.z, hq4.w,  9, a1, b1)                \
    KP(hq5.x, hq5.y, 10, a1, b1)  KP(hq5.z, hq5.w, 11, a1, b1)                \
    KP(hq6.x, hq6.y, 12, a1, b1)  KP(hq6.z, hq6.w, 13, a1, b1)                \
    KP(hq7.x, hq7.y, 14, a1, b1)  KP(hq7.z, hq7.w, 15, a1, b1)                \
    f32x2 sa = a0 + a1;                                                       \
    f32x2 sb = b0 + b1;                                                       \
    const float zA = sa.x + sa.y;   /* already scaled by -log2e */            \
    const float zB = sb.x + sb.y;   /* scaled by +2log2e / -log2e */          \
    if ((STOK) != 0) {                       /* wave-uniform branch */        \
      float eA = exp2f(zA);                                                   \
      float P  = frcp(1.0f + eA);                                             \
      float eB = exp2f(zB);                                                   \
      float rB = frcp(1.0f + eB);                                             \
      float Q  = fmaf(mB, rB, aB);                                            \
      float P2 = __shfl_xor(P, 32);                                           \
      float Q2 = __shfl_xor(Q, 32);                                           \
      float gi = lo ? P  : P2;                                                \
      float gf = lo ? P2 : P;                                                 \
      float gg = lo ? Q  : Q2;                                                \
      float go = lo ? Q2 : Q;                                                 \
      float cn = fmaf(gf, c, gi * gg);                                        \
      float eC = exp2f(cn * TWOLOG2E);                                        \
      float tc = fmaf(-2.0f, frcp(1.0f + eC), 1.0f);                          \
      float hn = go * tc;                                                     \
      c = cn; h = hn;                                                         \
      hbuf[kidx] = hn;                                                        \
      asm volatile("" ::: "memory");                                          \
    }                                                                         \
  }

__global__ __launch_bounds__(64, 3)
void lstm_pk2_kernel(const int*    __restrict__ tokens,
                     const float*  __restrict__ rec_kernel,  // [32][128]
                     const float2* __restrict__ proj2,       // [VOCAB][64] scaled
                     float*        __restrict__ out) {
  __shared__ int   tokl[520];      // 500 + pad
  __shared__ float hbuf[32];

  const int l   = threadIdx.x;     // 0..63
  const int row = blockIdx.x;
  const int kidx = l & 31;

  // ---- stage tokens (1 row, 500 ints) ----
  {
    const int4* src = reinterpret_cast<const int4*>(tokens + (size_t)row * T_N);
    for (int i = l; i < T_N / 4; i += 64)
      *reinterpret_cast<int4*>(&tokl[4 * i]) = src[i];
    if (l < 20) tokl[T_N + l] = 0;
  }
  if (l < 32) hbuf[l] = 0.0f;
  asm volatile("" ::: "memory");   // staging before scan reads (DS in-order per wave)

  const bool lo = (l < 32);
  const float mB = lo ? -2.0f : 1.0f;
  const float aB = lo ?  1.0f : 0.0f;
  const float sBw = lo ? TWOLOG2E : -LOG2E;

  // ---- paired pre-scaled weights:
  //   wA[k2] = {-log2e*R[2k2][l],   -log2e*R[2k2+1][l]}
  //   wB[k2] = { sBw  *R[2k2][64+l], sBw *R[2k2+1][64+l]}
  f32x2 wA[16], wB[16];
#pragma unroll
  for (int k2 = 0; k2 < 16; ++k2) {
    wA[k2] = (f32x2){ rec_kernel[(2 * k2) * 128 + l] * -LOG2E,
                      rec_kernel[(2 * k2 + 1) * 128 + l] * -LOG2E };
    wB[k2] = (f32x2){ rec_kernel[(2 * k2) * 128 + 64 + l] * sBw,
                      rec_kernel[(2 * k2 + 1) * 128 + 64 + l] * sBw };
  }

  float c = 0.0f, h = 0.0f;

  // ---- token pipeline, 4 deep (wave-uniform scalars) ----
  int t0 = __builtin_amdgcn_readfirstlane(tokl[0]);
  int t1 = __builtin_amdgcn_readfirstlane(tokl[1]);
  int t2 = __builtin_amdgcn_readfirstlane(tokl[2]);
  int t3 = __builtin_amdgcn_readfirstlane(tokl[3]);

  float2 p0 = proj2[(size_t)t0 * 64 + l];
  float2 p1 = proj2[(size_t)t1 * 64 + l];

#pragma unroll 1
  for (int t = 0; t < T_N; t += 2) {
    int2 tv = *reinterpret_cast<const int2*>(&tokl[t + 4]);

    STEP(t0, t2, p0);   // step t,   prefetch proj for t+2
    STEP(t1, t3, p1);   // step t+1, prefetch proj for t+3

    t0 = t2; t1 = t3;
    t2 = __builtin_amdgcn_readfirstlane(tv.x);
    t3 = __builtin_amdgcn_readfirstlane(tv.y);
  }

  if (l < 32) out[(size_t)row * HID_N + l] = h;
}

// ---------------------------------------------------------------------------
// Fallback (no workspace): proven round-1 kernel.
// ---------------------------------------------------------------------------
__device__ __forceinline__ float sigm_fb(float x) {
  return frcp(1.0f + exp2f(x * -1.4426950408889634f));
}
__device__ __forceinline__ float tanh_fb(float x) {
  float e = exp2f(x * 2.8853900817779268f);
  return fmaf(-2.0f, frcp(e + 1.0f), 1.0f);
}

__global__ __launch_bounds__(256, 2)
void lstm_scan_fallback(const int*   __restrict__ tokens,
                        const float* __restrict__ rec_kernel,
                        const float* __restrict__ emb,
                        const float* __restrict__ W,
                        const float* __restrict__ bias,
                        float*       __restrict__ out) {
  __shared__ int   tokl[8][T_N];
  __shared__ float hbuf[8][HID_N];

  const int tid  = threadIdx.x;
  const int wv   = tid >> 6;
  const int lane = tid & 63;
  const int half = lane >> 5;
  const int j    = lane & 31;
  const int wrow = wv * 2 + half;
  const int row  = blockIdx.x * 8 + wrow;

  {
    const int4* src = reinterpret_cast<const int4*>(tokens + (size_t)blockIdx.x * 8 * T_N);
    int4* dst = reinterpret_cast<int4*>(&tokl[0][0]);
    for (int i = tid; i < 8 * T_N / 4; i += 256) dst[i] = src[i];
  }

  float wr[HID_N][4];
#pragma unroll
  for (int k = 0; k < HID_N; ++k)
#pragma unroll
    for (int gg2 = 0; gg2 < 4; ++gg2) wr[k][gg2] = rec_kernel[k * 128 + gg2 * 32 + j];

  float wk[EMB_N][4];
  float bb[4];
#pragma unroll
  for (int e = 0; e < EMB_N; ++e)
#pragma unroll
    for (int gg2 = 0; gg2 < 4; ++gg2) wk[e][gg2] = W[e * 128 + gg2 * 32 + j];
#pragma unroll
  for (int gg2 = 0; gg2 < 4; ++gg2) bb[gg2] = bias[gg2 * 32 + j];
  __syncthreads();

  float c = 0.0f, h = 0.0f;
  float4 h4[8];
#pragma unroll
  for (int q = 0; q < 8; ++q) h4[q] = make_float4(0.f, 0.f, 0.f, 0.f);

  for (int t = 0; t < T_N; ++t) {
    const int tokc = tokl[wrow][t];
    const float4* ev = reinterpret_cast<const float4*>(emb + (size_t)tokc * EMB_N);
    float4 e0 = ev[0], e1 = ev[1], e2 = ev[2], e3 = ev[3];
    const float em[16] = {e0.x,e0.y,e0.z,e0.w, e1.x,e1.y,e1.z,e1.w,
                          e2.x,e2.y,e2.z,e2.w, e3.x,e3.y,e3.z,e3.w};
    float a0 = bb[0], a1 = bb[1], a2 = bb[2], a3 = bb[3];
#pragma unroll
    for (int e = 0; e < EMB_N; ++e) {
      float x = em[e];
      a0 = fmaf(x, wk[e][0], a0); a1 = fmaf(x, wk[e][1], a1);
      a2 = fmaf(x, wk[e][2], a2); a3 = fmaf(x, wk[e][3], a3);
    }
#pragma unroll
    for (int q = 0; q < 8; ++q) {
      float hx = h4[q].x, hy = h4[q].y, hz = h4[q].z, hw = h4[q].w;
      a0 = fmaf(hx, wr[4*q+0][0], a0); a1 = fmaf(hx, wr[4*q+0][1], a1);
      a2 = fmaf(hx, wr[4*q+0][2], a2); a3 = fmaf(hx, wr[4*q+0][3], a3);
      a0 = fmaf(hy, wr[4*q+1][0], a0); a1 = fmaf(hy, wr[4*q+1][1], a1);
      a2 = fmaf(hy, wr[4*q+1][2], a2); a3 = fmaf(hy, wr[4*q+1][3], a3);
      a0 = fmaf(hz, wr[4*q+2][0], a0); a1 = fmaf(hz, wr[4*q+2][1], a1);
      a2 = fmaf(hz, wr[4*q+2][2], a2); a3 = fmaf(hz, wr[4*q+2][3], a3);
      a0 = fmaf(hw, wr[4*q+3][0], a0); a1 = fmaf(hw, wr[4*q+3][1], a1);
      a2 = fmaf(hw, wr[4*q+3][2], a2); a3 = fmaf(hw, wr[4*q+3][3], a3);
    }
    float ig = sigm_fb(a0), fg = sigm_fb(a1), gg = tanh_fb(a2), og = sigm_fb(a3);
    float cn = fmaf(fg, c, ig * gg);
    float hn = og * tanh_fb(cn);
    if (tokc != 0) { h = hn; c = cn; }
    hbuf[wrow][j] = h;
    asm volatile("" ::: "memory");
#pragma unroll
    for (int q = 0; q < 8; ++q)
      h4[q] = reinterpret_cast<const float4*>(&hbuf[wrow][0])[q];
    asm volatile("" ::: "memory");
  }
  out[(size_t)row * HID_N + j] = h;
}

extern "C" void kernel_launch(void* const* d_in, const int* in_sizes, int n_in,
                              void* d_out, int out_size, void* d_ws, size_t ws_size,
                              hipStream_t stream) {
  const int*   tokens = (const int*)  d_in[0];
  const float* emb    = (const float*)d_in[1];
  const float* W      = (const float*)d_in[2];
  const float* rec    = (const float*)d_in[3];
  const float* bias   = (const float*)d_in[4];
  float* out = (float*)d_out;

  const size_t need = (size_t)VOCAB_N * 64 * sizeof(float2);  // 25.6 MB
  if (ws_size >= need) {
    float2* proj2 = (float2*)d_ws;
    build_proj2s_kernel<<<(VOCAB_N * 64) / 256 + 1, 256, 0, stream>>>(emb, W, bias, proj2);
    lstm_pk2_kernel<<<B_N, 64, 0, stream>>>(tokens, rec, proj2, out);
  } else {
    lstm_scan_fallback<<<B_N / 8, 256, 0, stream>>>(tokens, rec, emb, W, bias, out);
  }
}